// Round 5
// baseline (1823.248 us; speedup 1.0000x reference)
//
#include <hip/hip_runtime.h>
#include <math.h>

#define N_ROWS 12288
#define DIM 256
#define K_TOP 32
#define CAP 256          // candidate slots per row
#define T0 0.145f        // push threshold; mean candidates/row ~125, P(<32) ~ 0

// ---------------- key helpers ----------------
__device__ __forceinline__ unsigned int f2key(float f) {
    unsigned int u = __float_as_uint(f);
    return (u & 0x80000000u) ? ~u : (u | 0x80000000u);
}
__device__ __forceinline__ float key2f(unsigned int k) {
    unsigned int u = (k & 0x80000000u) ? (k ^ 0x80000000u) : ~k;
    return __uint_as_float(u);
}
__device__ __forceinline__ unsigned long long composite(float v, int j) {
    return ((unsigned long long)f2key(v) << 32) | (unsigned int)(N_ROWS - j);
}
__device__ __forceinline__ unsigned long long shfl_xor_u64(unsigned long long x, int m) {
    unsigned int lo = (unsigned int)x, hi = (unsigned int)(x >> 32);
    lo = __shfl_xor(lo, m, 64);
    hi = __shfl_xor(hi, m, 64);
    return ((unsigned long long)hi << 32) | lo;
}
__device__ __forceinline__ unsigned long long shfl_down_u64(unsigned long long x, int off) {
    unsigned int lo = (unsigned int)x, hi = (unsigned int)(x >> 32);
    lo = __shfl_down(lo, off, 64);
    hi = __shfl_down(hi, off, 64);
    return ((unsigned long long)hi << 32) | lo;
}

// ---------------- Kernel 1: L2 row normalize ----------------
__global__ __launch_bounds__(256) void normalize_rows(const float* __restrict__ x,
                                                      float* __restrict__ xn) {
    int row = blockIdx.x;
    int t = threadIdx.x;
    float v = x[(size_t)row * DIM + t];
    float sq = v * v;
    #pragma unroll
    for (int off = 32; off > 0; off >>= 1)
        sq += __shfl_down(sq, off, 64);
    __shared__ float ws[4];
    if ((t & 63) == 0) ws[t >> 6] = sq;
    __syncthreads();
    float total = ws[0] + ws[1] + ws[2] + ws[3];
    float norm = fmaxf(sqrtf(total), 1e-12f);
    xn[(size_t)row * DIM + t] = v / norm;
}

// ---------------- GEMM core (shared between paths) ----------------
// NOTE: all acc[][] indices must be compile-time (runtime index => scratch
// demotion, Round 3: 27 GB scratch traffic, 15x regression).
#define BM 128
#define BN 128
#define BK 16
#define BMP 132
#define TRP 140
#define NT (N_ROWS / BM)   // 96

#define AS(buf, k, r) smem[(buf)*(2*BK*BMP) + (k)*BMP + (r)]
#define BS(buf, k, r) smem[(buf)*(2*BK*BMP) + (BK*BMP) + (k)*BMP + (r)]
#define TRS(r, c)     smem[(r)*TRP + (c)]

#define GEMM_BODY                                                              \
    int L = blockIdx.x;                                                        \
    int bi = (int)((sqrtf(8.0f * (float)L + 1.0f) - 1.0f) * 0.5f);             \
    while ((bi + 1) * (bi + 2) / 2 <= L) ++bi;                                 \
    while (bi * (bi + 1) / 2 > L) --bi;                                        \
    int bj = L - bi * (bi + 1) / 2;                                            \
    int tid = threadIdx.x;                                                     \
    int tx = tid & 15, ty = tid >> 4;                                          \
    int tx4 = tx * 4, ty4 = ty * 4;                                            \
    int r0 = tid >> 2, q0 = tid & 3;                                           \
    const float* Abase = A + (size_t)(bi * BM) * DIM;                          \
    const float* Bbase = A + (size_t)(bj * BN) * DIM;                          \
    float acc[8][8] = {};                                                      \
    float4 pa0, pa1, pb0, pb1;                                                 \
    pa0 = *(const float4*)(Abase + (size_t)r0 * DIM + q0 * 4);                 \
    pa1 = *(const float4*)(Abase + (size_t)(r0 + 64) * DIM + q0 * 4);          \
    pb0 = *(const float4*)(Bbase + (size_t)r0 * DIM + q0 * 4);                 \
    pb1 = *(const float4*)(Bbase + (size_t)(r0 + 64) * DIM + q0 * 4);          \
    {                                                                          \
        const float* a0 = (const float*)&pa0; const float* a1 = (const float*)&pa1; \
        const float* b0 = (const float*)&pb0; const float* b1 = (const float*)&pb1; \
        _Pragma("unroll")                                                      \
        for (int c = 0; c < 4; ++c) {                                          \
            AS(0, q0 * 4 + c, r0) = a0[c];  AS(0, q0 * 4 + c, r0 + 64) = a1[c];\
            BS(0, q0 * 4 + c, r0) = b0[c];  BS(0, q0 * 4 + c, r0 + 64) = b1[c];\
        }                                                                      \
    }                                                                          \
    __syncthreads();                                                           \
    int p = 0;                                                                 \
    _Pragma("unroll 1")                                                        \
    for (int it = 0; it < DIM / BK; ++it) {                                    \
        bool has_next = (it + 1) < (DIM / BK);                                 \
        if (has_next) {                                                        \
            int k0 = (it + 1) * BK;                                            \
            pa0 = *(const float4*)(Abase + (size_t)r0 * DIM + k0 + q0 * 4);    \
            pa1 = *(const float4*)(Abase + (size_t)(r0 + 64) * DIM + k0 + q0 * 4); \
            pb0 = *(const float4*)(Bbase + (size_t)r0 * DIM + k0 + q0 * 4);    \
            pb1 = *(const float4*)(Bbase + (size_t)(r0 + 64) * DIM + k0 + q0 * 4); \
        }                                                                      \
        _Pragma("unroll")                                                      \
        for (int kk = 0; kk < BK; ++kk) {                                      \
            float a[8], b[8];                                                  \
            *(float4*)&a[0] = *(const float4*)&AS(p, kk, ty4);                 \
            *(float4*)&a[4] = *(const float4*)&AS(p, kk, ty4 + 64);            \
            *(float4*)&b[0] = *(const float4*)&BS(p, kk, tx4);                 \
            *(float4*)&b[4] = *(const float4*)&BS(p, kk, tx4 + 64);            \
            _Pragma("unroll")                                                  \
            for (int i = 0; i < 8; ++i)                                        \
                _Pragma("unroll")                                              \
                for (int j = 0; j < 8; ++j)                                    \
                    acc[i][j] = fmaf(a[i], b[j], acc[i][j]);                   \
        }                                                                      \
        if (has_next) {                                                        \
            int np = p ^ 1;                                                    \
            const float* a0 = (const float*)&pa0; const float* a1 = (const float*)&pa1; \
            const float* b0 = (const float*)&pb0; const float* b1 = (const float*)&pb1; \
            _Pragma("unroll")                                                  \
            for (int c = 0; c < 4; ++c) {                                      \
                AS(np, q0 * 4 + c, r0) = a0[c];  AS(np, q0 * 4 + c, r0 + 64) = a1[c]; \
                BS(np, q0 * 4 + c, r0) = b0[c];  BS(np, q0 * 4 + c, r0 + 64) = b1[c]; \
            }                                                                  \
        }                                                                      \
        __syncthreads();                                                       \
        p ^= 1;                                                                \
    }

// ---------------- Kernel 2a (fused path): GEMM + candidate push ----------------
__device__ __forceinline__ void push_cand(unsigned long long* cand, int* counts,
                                          int r, int c, float v) {
    int slot = atomicAdd(&counts[r], 1);
    if (slot < CAP) cand[(size_t)r * CAP + slot] = composite(v, c);
}

__global__ __launch_bounds__(256) void gemm_push(const float* __restrict__ A,
                                                 unsigned long long* __restrict__ cand,
                                                 int* __restrict__ counts) {
    __shared__ float smem[2 * 2 * BK * BMP];
    GEMM_BODY
    // epilogue: push candidates to row lists (both orientations; no dense C)
    #pragma unroll
    for (int i = 0; i < 8; ++i) {
        int gr = bi * BM + ty4 + (i & 3) + (i >> 2) * 64;
        #pragma unroll
        for (int j = 0; j < 8; ++j) {
            int gc = bj * BN + tx4 + (j & 3) + (j >> 2) * 64;
            float v = acc[i][j];
            if (v > T0) {
                push_cand(cand, counts, gr, gc, v);
                if (bi != bj) push_cand(cand, counts, gc, gr, v);
            }
        }
    }
}

// ---------------- Kernel 3a (fused path): select top-32 + scatter ----------------
__global__ __launch_bounds__(256) void select_scatter(const unsigned long long* __restrict__ cand,
                                                      const int* __restrict__ counts,
                                                      int* __restrict__ flags,
                                                      float* __restrict__ out) {
    __shared__ unsigned long long bt[256];
    __shared__ unsigned long long bc64;
    int row = blockIdx.x;
    int t = threadIdx.x;
    int cnt = counts[row];
    if (cnt < K_TOP || cnt > CAP) {        // deficient or overflowed -> rescue
        if (t == 0) flags[row] = 1;
        return;
    }
    int M = cnt;
    unsigned long long v = (t < M) ? cand[(size_t)row * CAP + t] : 0ULL;
    #pragma unroll 1
    for (int k = 2; k <= 256; k <<= 1) {
        #pragma unroll 1
        for (int j = k >> 1; j >= 1; j >>= 1) {
            unsigned long long other;
            if (j >= 64) {
                bt[t] = v;
                __syncthreads();
                other = bt[t ^ j];
                __syncthreads();
            } else {
                other = shfl_xor_u64(v, j);
            }
            bool down = ((t & k) == 0);
            bool lower = ((t & j) == 0);
            bool take_max = (down == lower);
            bool omax = (other > v);
            v = (take_max == omax) ? other : v;
        }
    }
    if (t == 31) bc64 = v;
    __syncthreads();
    unsigned long long cutoff = bc64;
    if (t < M) {
        unsigned long long comp = cand[(size_t)row * CAP + t];
        if (comp >= cutoff) {
            int col = N_ROWS - (int)(comp & 0xFFFFFFFFu);
            out[(size_t)row * N_ROWS + col] = key2f((unsigned int)(comp >> 32));
        }
    }
}

// ---------------- Kernel 4a (fused path): exact rescue for flagged rows ----------------
__global__ __launch_bounds__(256) void rescue_rows(const float* __restrict__ xn,
                                                   const int* __restrict__ flags,
                                                   float* __restrict__ out) {
    int row = blockIdx.x;
    if (!flags[row]) return;               // expected: always (early exit)
    __shared__ float xrow[DIM];
    __shared__ float sims[N_ROWS];         // 48 KB
    __shared__ unsigned long long red[4];
    __shared__ unsigned long long bc64;
    int t = threadIdx.x;
    xrow[t] = xn[(size_t)row * DIM + t];
    __syncthreads();
    for (int j = t; j < N_ROWS; j += 256) {
        const float* cp = xn + (size_t)j * DIM;
        float s = 0.0f;
        for (int d = 0; d < DIM; d += 4) {
            float4 w = *(const float4*)(cp + d);
            s = fmaf(xrow[d], w.x, s); s = fmaf(xrow[d + 1], w.y, s);
            s = fmaf(xrow[d + 2], w.z, s); s = fmaf(xrow[d + 3], w.w, s);
        }
        sims[j] = s;
    }
    __syncthreads();
    #pragma unroll 1
    for (int r2 = 0; r2 < K_TOP; ++r2) {
        unsigned long long best = 0;
        for (int k = 0; k < N_ROWS / 256; ++k) {
            int j = t + 256 * k;
            unsigned long long c = composite(sims[j], j);
            if (c > best) best = c;
        }
        #pragma unroll
        for (int off = 32; off > 0; off >>= 1) {
            unsigned long long o = shfl_down_u64(best, off);
            if (o > best) best = o;
        }
        if ((t & 63) == 0) red[t >> 6] = best;
        __syncthreads();
        if (t == 0) {
            unsigned long long win = red[0];
            if (red[1] > win) win = red[1];
            if (red[2] > win) win = red[2];
            if (red[3] > win) win = red[3];
            bc64 = win;
            int jwin = N_ROWS - (int)(win & 0xFFFFFFFFu);
            out[(size_t)row * N_ROWS + jwin] = key2f((unsigned int)(win >> 32));
            sims[jwin] = -1e30f;
        }
        __syncthreads();
    }
}

// ---------------- Fallback path (ws too small): dense adj + streamed topk ----------------
__global__ __launch_bounds__(256) void gemm_sym_dense(const float* __restrict__ A,
                                                      float* __restrict__ C) {
    __shared__ float smem[2 * 2 * BK * BMP];
    GEMM_BODY
    #pragma unroll
    for (int i = 0; i < 8; ++i) {
        int rl = ty4 + (i & 3) + (i >> 2) * 64;
        float* outp = C + (size_t)(bi * BM + rl) * N_ROWS + bj * BN;
        *(float4*)(outp + tx4)      = *(float4*)&acc[i][0];
        *(float4*)(outp + 64 + tx4) = *(float4*)&acc[i][4];
    }
    if (bi == bj) return;
    #pragma unroll
    for (int c4 = 0; c4 < 4; ++c4) {
        __syncthreads();
        if ((tx >> 3) == (c4 & 1)) {
            #pragma unroll
            for (int j03 = 0; j03 < 4; ++j03)
                #pragma unroll
                for (int i = 0; i < 8; ++i) {
                    int rl = ty4 + (i & 3) + (i >> 2) * 64;
                    TRS((tx & 7) * 4 + j03, rl) = acc[i][(c4 >> 1) * 4 + j03];
                }
        }
        __syncthreads();
        int rr = tid >> 3;
        int cc = (tid & 7) * 16;
        float* dst = C + (size_t)(bj * BN + c4 * 32 + rr) * N_ROWS + bi * BM + cc;
        *(float4*)(dst + 0)  = *(const float4*)&TRS(rr, cc + 0);
        *(float4*)(dst + 4)  = *(const float4*)&TRS(rr, cc + 4);
        *(float4*)(dst + 8)  = *(const float4*)&TRS(rr, cc + 8);
        *(float4*)(dst + 12) = *(const float4*)&TRS(rr, cc + 12);
    }
}

#define CAND_CAP 2048
__global__ __launch_bounds__(256, 4) void topk_mask(float* __restrict__ adj) {
    __shared__ float cval[CAND_CAP];
    __shared__ int cidx[CAND_CAP];
    __shared__ int count;
    __shared__ unsigned long long bt[256];
    __shared__ unsigned long long red[4];
    __shared__ unsigned long long bc64;
    int row = blockIdx.x;
    int t = threadIdx.x;
    float* rp = adj + (size_t)row * N_ROWS;
    const float4* rp4 = (const float4*)rp;
    float T = T0;
    int M;
    #pragma unroll 1
    while (true) {
        if (t == 0) count = 0;
        __syncthreads();
        #pragma unroll 1
        for (int c = 0; c < 12; ++c) {
            float4 w = rp4[c * 256 + t];
            int jb = 4 * (c * 256 + t);
            if (w.x > T) { int p = atomicAdd(&count, 1); if (p < CAND_CAP) { cval[p] = w.x; cidx[p] = jb + 0; } }
            if (w.y > T) { int p = atomicAdd(&count, 1); if (p < CAND_CAP) { cval[p] = w.y; cidx[p] = jb + 1; } }
            if (w.z > T) { int p = atomicAdd(&count, 1); if (p < CAND_CAP) { cval[p] = w.z; cidx[p] = jb + 2; } }
            if (w.w > T) { int p = atomicAdd(&count, 1); if (p < CAND_CAP) { cval[p] = w.w; cidx[p] = jb + 3; } }
        }
        __syncthreads();
        M = count < CAND_CAP ? count : CAND_CAP;
        if (M >= K_TOP) break;
        T -= 0.03f;
        __syncthreads();
    }
    unsigned long long cutoff;
    if (M <= 256) {
        unsigned long long v = (t < M) ? composite(cval[t], cidx[t]) : 0ULL;
        #pragma unroll 1
        for (int k = 2; k <= 256; k <<= 1) {
            #pragma unroll 1
            for (int j = k >> 1; j >= 1; j >>= 1) {
                unsigned long long other;
                if (j >= 64) {
                    bt[t] = v;
                    __syncthreads();
                    other = bt[t ^ j];
                    __syncthreads();
                } else {
                    other = shfl_xor_u64(v, j);
                }
                bool down = ((t & k) == 0);
                bool lower = ((t & j) == 0);
                bool take_max = (down == lower);
                bool omax = (other > v);
                v = (take_max == omax) ? other : v;
            }
        }
        if (t == 31) bc64 = v;
        __syncthreads();
        cutoff = bc64;
    } else {
        cutoff = 0;
        #pragma unroll 1
        for (int r2 = 0; r2 < K_TOP; ++r2) {
            unsigned long long best = 0;
            for (int p2 = t; p2 < M; p2 += 256) {
                int id = cidx[p2];
                if (id >= 0) {
                    unsigned long long comp = composite(cval[p2], id);
                    if (comp > best) best = comp;
                }
            }
            #pragma unroll
            for (int off = 32; off > 0; off >>= 1) {
                unsigned long long o = shfl_down_u64(best, off);
                if (o > best) best = o;
            }
            if ((t & 63) == 0) red[t >> 6] = best;
            __syncthreads();
            unsigned long long win = red[0];
            if (red[1] > win) win = red[1];
            if (red[2] > win) win = red[2];
            if (red[3] > win) win = red[3];
            cutoff = win;
            int jwin = N_ROWS - (int)(win & 0xFFFFFFFFu);
            __syncthreads();
            for (int p2 = t; p2 < M; p2 += 256)
                if (cidx[p2] == jwin) cidx[p2] = -1;
            __syncthreads();
        }
    }
    #pragma unroll 1
    for (int c = 0; c < 12; ++c) {
        float4 w = rp4[c * 256 + t];
        int jb = 4 * (c * 256 + t);
        float4 o;
        o.x = (composite(w.x, jb + 0) >= cutoff) ? w.x : 0.0f;
        o.y = (composite(w.y, jb + 1) >= cutoff) ? w.y : 0.0f;
        o.z = (composite(w.z, jb + 2) >= cutoff) ? w.z : 0.0f;
        o.w = (composite(w.w, jb + 3) >= cutoff) ? w.w : 0.0f;
        ((float4*)rp)[c * 256 + t] = o;
    }
}

extern "C" void kernel_launch(void* const* d_in, const int* in_sizes, int n_in,
                              void* d_out, int out_size, void* d_ws, size_t ws_size,
                              hipStream_t stream) {
    const float* x = (const float*)d_in[0];
    float* out = (float*)d_out;

    // ws layout (fused path):
    //   xn:     12288*256*4            = 12,582,912 B
    //   counts: 12288*4                =     49,152 B
    //   flags:  12288*4                =     49,152 B
    //   cand:   12288*CAP*8            = 25,165,824 B
    const size_t xn_b = (size_t)N_ROWS * DIM * 4;
    const size_t cnt_b = (size_t)N_ROWS * 4;
    const size_t need = xn_b + 2 * cnt_b + (size_t)N_ROWS * CAP * 8;

    float* xn = (float*)d_ws;
    normalize_rows<<<N_ROWS, 256, 0, stream>>>(x, xn);

    if (ws_size >= need) {
        int* counts = (int*)((char*)d_ws + xn_b);
        int* flags = (int*)((char*)d_ws + xn_b + cnt_b);
        unsigned long long* cand = (unsigned long long*)((char*)d_ws + xn_b + 2 * cnt_b);
        hipMemsetAsync(counts, 0, 2 * cnt_b, stream);           // counts + flags
        hipMemsetAsync(out, 0, (size_t)out_size * 4, stream);   // dense zero output
        gemm_push<<<NT * (NT + 1) / 2, 256, 0, stream>>>(xn, cand, counts);
        select_scatter<<<N_ROWS, 256, 0, stream>>>(cand, counts, flags, out);
        rescue_rows<<<N_ROWS, 256, 0, stream>>>(xn, flags, out);
    } else {
        gemm_sym_dense<<<NT * (NT + 1) / 2, 256, 0, stream>>>(xn, out);
        topk_mask<<<N_ROWS, 256, 0, stream>>>(out);
    }
}

// Round 6
// 1565.608 us; speedup vs baseline: 1.1646x; 1.1646x over previous
//
#include <hip/hip_runtime.h>
#include <math.h>

#define N_ROWS 12288
#define DIM 256
#define K_TOP 32
#define CAP 256          // candidate slots per row
#define T0 0.145f        // push threshold; mean candidates/row ~125
#define ECAP 2048        // block-local LDS entry cap (expected ~330/block)

// ---------------- key helpers ----------------
__device__ __forceinline__ unsigned int f2key(float f) {
    unsigned int u = __float_as_uint(f);
    return (u & 0x80000000u) ? ~u : (u | 0x80000000u);
}
__device__ __forceinline__ float key2f(unsigned int k) {
    unsigned int u = (k & 0x80000000u) ? (k ^ 0x80000000u) : ~k;
    return __uint_as_float(u);
}
__device__ __forceinline__ unsigned long long composite(float v, int j) {
    return ((unsigned long long)f2key(v) << 32) | (unsigned int)(N_ROWS - j);
}
__device__ __forceinline__ unsigned long long shfl_xor_u64(unsigned long long x, int m) {
    unsigned int lo = (unsigned int)x, hi = (unsigned int)(x >> 32);
    lo = __shfl_xor(lo, m, 64);
    hi = __shfl_xor(hi, m, 64);
    return ((unsigned long long)hi << 32) | lo;
}
__device__ __forceinline__ unsigned long long shfl_down_u64(unsigned long long x, int off) {
    unsigned int lo = (unsigned int)x, hi = (unsigned int)(x >> 32);
    lo = __shfl_down(lo, off, 64);
    hi = __shfl_down(hi, off, 64);
    return ((unsigned long long)hi << 32) | lo;
}

// ---------------- Kernel 1: L2 row normalize ----------------
__global__ __launch_bounds__(256) void normalize_rows(const float* __restrict__ x,
                                                      float* __restrict__ xn) {
    int row = blockIdx.x;
    int t = threadIdx.x;
    float v = x[(size_t)row * DIM + t];
    float sq = v * v;
    #pragma unroll
    for (int off = 32; off > 0; off >>= 1)
        sq += __shfl_down(sq, off, 64);
    __shared__ float ws[4];
    if ((t & 63) == 0) ws[t >> 6] = sq;
    __syncthreads();
    float total = ws[0] + ws[1] + ws[2] + ws[3];
    float norm = fmaxf(sqrtf(total), 1e-12f);
    xn[(size_t)row * DIM + t] = v / norm;
}

// ---------------- GEMM core (shared) ----------------
// NOTE: all acc[][] indices must be compile-time (runtime index => scratch
// demotion, Round 3: 27 GB scratch traffic, 15x regression).
#define BM 128
#define BN 128
#define BK 16
#define BMP 132
#define TRP 140
#define NT (N_ROWS / BM)   // 96

#define AS(buf, k, r) smem[(buf)*(2*BK*BMP) + (k)*BMP + (r)]
#define BS(buf, k, r) smem[(buf)*(2*BK*BMP) + (BK*BMP) + (k)*BMP + (r)]
#define TRS(r, c)     smem[(r)*TRP + (c)]

#define GEMM_BODY                                                              \
    int L = blockIdx.x;                                                        \
    int bi = (int)((sqrtf(8.0f * (float)L + 1.0f) - 1.0f) * 0.5f);             \
    while ((bi + 1) * (bi + 2) / 2 <= L) ++bi;                                 \
    while (bi * (bi + 1) / 2 > L) --bi;                                        \
    int bj = L - bi * (bi + 1) / 2;                                            \
    int tid = threadIdx.x;                                                     \
    int tx = tid & 15, ty = tid >> 4;                                          \
    int tx4 = tx * 4, ty4 = ty * 4;                                            \
    int r0 = tid >> 2, q0 = tid & 3;                                           \
    const float* Abase = A + (size_t)(bi * BM) * DIM;                          \
    const float* Bbase = A + (size_t)(bj * BN) * DIM;                          \
    float acc[8][8] = {};                                                      \
    float4 pa0, pa1, pb0, pb1;                                                 \
    pa0 = *(const float4*)(Abase + (size_t)r0 * DIM + q0 * 4);                 \
    pa1 = *(const float4*)(Abase + (size_t)(r0 + 64) * DIM + q0 * 4);          \
    pb0 = *(const float4*)(Bbase + (size_t)r0 * DIM + q0 * 4);                 \
    pb1 = *(const float4*)(Bbase + (size_t)(r0 + 64) * DIM + q0 * 4);          \
    {                                                                          \
        const float* a0 = (const float*)&pa0; const float* a1 = (const float*)&pa1; \
        const float* b0 = (const float*)&pb0; const float* b1 = (const float*)&pb1; \
        _Pragma("unroll")                                                      \
        for (int c = 0; c < 4; ++c) {                                          \
            AS(0, q0 * 4 + c, r0) = a0[c];  AS(0, q0 * 4 + c, r0 + 64) = a1[c];\
            BS(0, q0 * 4 + c, r0) = b0[c];  BS(0, q0 * 4 + c, r0 + 64) = b1[c];\
        }                                                                      \
    }                                                                          \
    __syncthreads();                                                           \
    int p = 0;                                                                 \
    _Pragma("unroll 1")                                                        \
    for (int it = 0; it < DIM / BK; ++it) {                                    \
        bool has_next = (it + 1) < (DIM / BK);                                 \
        if (has_next) {                                                        \
            int k0 = (it + 1) * BK;                                            \
            pa0 = *(const float4*)(Abase + (size_t)r0 * DIM + k0 + q0 * 4);    \
            pa1 = *(const float4*)(Abase + (size_t)(r0 + 64) * DIM + k0 + q0 * 4); \
            pb0 = *(const float4*)(Bbase + (size_t)r0 * DIM + k0 + q0 * 4);    \
            pb1 = *(const float4*)(Bbase + (size_t)(r0 + 64) * DIM + k0 + q0 * 4); \
        }                                                                      \
        _Pragma("unroll")                                                      \
        for (int kk = 0; kk < BK; ++kk) {                                      \
            float a[8], b[8];                                                  \
            *(float4*)&a[0] = *(const float4*)&AS(p, kk, ty4);                 \
            *(float4*)&a[4] = *(const float4*)&AS(p, kk, ty4 + 64);            \
            *(float4*)&b[0] = *(const float4*)&BS(p, kk, tx4);                 \
            *(float4*)&b[4] = *(const float4*)&BS(p, kk, tx4 + 64);            \
            _Pragma("unroll")                                                  \
            for (int i = 0; i < 8; ++i)                                        \
                _Pragma("unroll")                                              \
                for (int j = 0; j < 8; ++j)                                    \
                    acc[i][j] = fmaf(a[i], b[j], acc[i][j]);                   \
        }                                                                      \
        if (has_next) {                                                        \
            int np = p ^ 1;                                                    \
            const float* a0 = (const float*)&pa0; const float* a1 = (const float*)&pa1; \
            const float* b0 = (const float*)&pb0; const float* b1 = (const float*)&pb1; \
            _Pragma("unroll")                                                  \
            for (int c = 0; c < 4; ++c) {                                      \
                AS(np, q0 * 4 + c, r0) = a0[c];  AS(np, q0 * 4 + c, r0 + 64) = a1[c]; \
                BS(np, q0 * 4 + c, r0) = b0[c];  BS(np, q0 * 4 + c, r0 + 64) = b1[c]; \
            }                                                                  \
        }                                                                      \
        __syncthreads();                                                       \
        p ^= 1;                                                                \
    }

// ---------------- Kernel 2a: GEMM + LDS-aggregated candidate push ----------------
// Epilogue re-aliases smem: entry list (u64: key<<32 | rowlocal<<14 | col)
// pushed via one LDS counter; per-row counts aggregated in LDS; ONE global
// atomicAdd per (block, row) reserves contiguous slots; then scatter.
// rowlocal 0..127 = A-rows (target gr), 128..255 = B-rows (target gc).
__global__ __launch_bounds__(256) void gemm_push(const float* __restrict__ A,
                                                 unsigned long long* __restrict__ cand,
                                                 int* __restrict__ counts) {
    __shared__ float smem[2 * 2 * BK * BMP];   // 33792 B
    GEMM_BODY

    __syncthreads();   // K-loop LDS dead; re-alias
    unsigned int* lcount = (unsigned int*)smem;          // [1]
    unsigned int* cnt2   = (unsigned int*)smem + 8;      // [256] per-row totals
    unsigned int* cnt3   = (unsigned int*)smem + 264;    // [256] running offsets
    unsigned int* basep  = (unsigned int*)smem + 520;    // [256] reserved bases
    unsigned long long* ent = (unsigned long long*)((unsigned int*)smem + 776 + (776 & 1));
    // ent: ECAP * 8 B = 16 KB; total epilogue LDS ~19.2 KB < 33 KB. OK.

    if (tid == 0) *lcount = 0;
    cnt2[tid] = 0;
    cnt3[tid] = 0;
    __syncthreads();

    bool diag = (bi == bj);
    #pragma unroll
    for (int i = 0; i < 8; ++i) {
        int rlA = ty4 + (i & 3) + (i >> 2) * 64;          // local A-row
        #pragma unroll
        for (int j = 0; j < 8; ++j) {
            float v = acc[i][j];
            if (v > T0) {
                int clB = tx4 + (j & 3) + (j >> 2) * 64;  // local B-row
                int gr = bi * BM + rlA;
                int gc = bj * BN + clB;
                unsigned int key = f2key(v);
                // push to row gr (partner col gc)
                {
                    unsigned int s = atomicAdd(lcount, 1u);
                    if (s < ECAP) {
                        ent[s] = ((unsigned long long)key << 32) |
                                 ((unsigned int)rlA << 14) | (unsigned int)gc;
                        atomicAdd(&cnt2[rlA], 1u);
                    } else {   // overflow: exact direct path (~never)
                        int gs = atomicAdd(&counts[gr], 1);
                        if (gs < CAP) cand[(size_t)gr * CAP + gs] = composite(v, gc);
                    }
                }
                if (!diag) {   // mirror: row gc, partner col gr
                    unsigned int s = atomicAdd(lcount, 1u);
                    if (s < ECAP) {
                        ent[s] = ((unsigned long long)key << 32) |
                                 ((unsigned int)(128 + clB) << 14) | (unsigned int)gr;
                        atomicAdd(&cnt2[128 + clB], 1u);
                    } else {
                        int gs = atomicAdd(&counts[gc], 1);
                        if (gs < CAP) cand[(size_t)gc * CAP + gs] = composite(v, gr);
                    }
                }
            }
        }
    }
    __syncthreads();

    // reserve contiguous global slot ranges: one atomic per (block, local row)
    {
        unsigned int c = cnt2[tid];
        if (c > 0) {
            int grow = (tid < 128) ? (bi * BM + tid) : (bj * BN + (tid - 128));
            basep[tid] = (unsigned int)atomicAdd(&counts[grow], (int)c);
        }
    }
    __syncthreads();

    // scatter entries to reserved slots
    unsigned int nloc = *lcount;
    if (nloc > ECAP) nloc = ECAP;
    for (unsigned int e = tid; e < nloc; e += 256) {
        unsigned long long en = ent[e];
        unsigned int lo = (unsigned int)en;
        int rl = (int)((lo >> 14) & 0xFFu);
        int col = (int)(lo & 0x3FFFu);
        unsigned int key = (unsigned int)(en >> 32);
        unsigned int off = atomicAdd(&cnt3[rl], 1u);
        unsigned int slot = basep[rl] + off;
        if (slot < CAP) {
            int grow = (rl < 128) ? (bi * BM + rl) : (bj * BN + (rl - 128));
            cand[(size_t)grow * CAP + slot] =
                ((unsigned long long)key << 32) | (unsigned int)(N_ROWS - col);
        }
    }
}

// ---------------- Kernel 3a: select top-32 + scatter ----------------
__global__ __launch_bounds__(256) void select_scatter(const unsigned long long* __restrict__ cand,
                                                      const int* __restrict__ counts,
                                                      int* __restrict__ flags,
                                                      float* __restrict__ out) {
    __shared__ unsigned long long bt[256];
    __shared__ unsigned long long bc64;
    int row = blockIdx.x;
    int t = threadIdx.x;
    int cnt = counts[row];
    if (cnt < K_TOP || cnt > CAP) {        // deficient or overflowed -> rescue
        if (t == 0) flags[row] = 1;
        return;
    }
    int M = cnt;
    unsigned long long v = (t < M) ? cand[(size_t)row * CAP + t] : 0ULL;
    #pragma unroll 1
    for (int k = 2; k <= 256; k <<= 1) {
        #pragma unroll 1
        for (int j = k >> 1; j >= 1; j >>= 1) {
            unsigned long long other;
            if (j >= 64) {
                bt[t] = v;
                __syncthreads();
                other = bt[t ^ j];
                __syncthreads();
            } else {
                other = shfl_xor_u64(v, j);
            }
            bool down = ((t & k) == 0);
            bool lower = ((t & j) == 0);
            bool take_max = (down == lower);
            bool omax = (other > v);
            v = (take_max == omax) ? other : v;
        }
    }
    if (t == 31) bc64 = v;
    __syncthreads();
    unsigned long long cutoff = bc64;
    if (t < M) {
        unsigned long long comp = cand[(size_t)row * CAP + t];
        if (comp >= cutoff) {
            int col = N_ROWS - (int)(comp & 0xFFFFFFFFu);
            out[(size_t)row * N_ROWS + col] = key2f((unsigned int)(comp >> 32));
        }
    }
}

// ---------------- Kernel 4a: exact rescue for flagged rows (~never) ----------------
__global__ __launch_bounds__(256) void rescue_rows(const float* __restrict__ xn,
                                                   const int* __restrict__ flags,
                                                   float* __restrict__ out) {
    int row = blockIdx.x;
    if (!flags[row]) return;
    __shared__ float xrow[DIM];
    __shared__ float sims[N_ROWS];
    __shared__ unsigned long long red[4];
    int t = threadIdx.x;
    xrow[t] = xn[(size_t)row * DIM + t];
    __syncthreads();
    for (int j = t; j < N_ROWS; j += 256) {
        const float* cp = xn + (size_t)j * DIM;
        float s = 0.0f;
        for (int d = 0; d < DIM; d += 4) {
            float4 w = *(const float4*)(cp + d);
            s = fmaf(xrow[d], w.x, s); s = fmaf(xrow[d + 1], w.y, s);
            s = fmaf(xrow[d + 2], w.z, s); s = fmaf(xrow[d + 3], w.w, s);
        }
        sims[j] = s;
    }
    __syncthreads();
    #pragma unroll 1
    for (int r2 = 0; r2 < K_TOP; ++r2) {
        unsigned long long best = 0;
        for (int k = 0; k < N_ROWS / 256; ++k) {
            int j = t + 256 * k;
            unsigned long long c = composite(sims[j], j);
            if (c > best) best = c;
        }
        #pragma unroll
        for (int off = 32; off > 0; off >>= 1) {
            unsigned long long o = shfl_down_u64(best, off);
            if (o > best) best = o;
        }
        if ((t & 63) == 0) red[t >> 6] = best;
        __syncthreads();
        if (t == 0) {
            unsigned long long win = red[0];
            if (red[1] > win) win = red[1];
            if (red[2] > win) win = red[2];
            if (red[3] > win) win = red[3];
            int jwin = N_ROWS - (int)(win & 0xFFFFFFFFu);
            out[(size_t)row * N_ROWS + jwin] = key2f((unsigned int)(win >> 32));
            sims[jwin] = -1e30f;
        }
        __syncthreads();
    }
}

// ---------------- Fallback path (ws too small): dense adj + streamed topk ----------------
__global__ __launch_bounds__(256) void gemm_sym_dense(const float* __restrict__ A,
                                                      float* __restrict__ C) {
    __shared__ float smem[2 * 2 * BK * BMP];
    GEMM_BODY
    #pragma unroll
    for (int i = 0; i < 8; ++i) {
        int rl = ty4 + (i & 3) + (i >> 2) * 64;
        float* outp = C + (size_t)(bi * BM + rl) * N_ROWS + bj * BN;
        *(float4*)(outp + tx4)      = *(float4*)&acc[i][0];
        *(float4*)(outp + 64 + tx4) = *(float4*)&acc[i][4];
    }
    if (bi == bj) return;
    #pragma unroll
    for (int c4 = 0; c4 < 4; ++c4) {
        __syncthreads();
        if ((tx >> 3) == (c4 & 1)) {
            #pragma unroll
            for (int j03 = 0; j03 < 4; ++j03)
                #pragma unroll
                for (int i = 0; i < 8; ++i) {
                    int rl = ty4 + (i & 3) + (i >> 2) * 64;
                    TRS((tx & 7) * 4 + j03, rl) = acc[i][(c4 >> 1) * 4 + j03];
                }
        }
        __syncthreads();
        int rr = tid >> 3;
        int cc = (tid & 7) * 16;
        float* dst = C + (size_t)(bj * BN + c4 * 32 + rr) * N_ROWS + bi * BM + cc;
        *(float4*)(dst + 0)  = *(const float4*)&TRS(rr, cc + 0);
        *(float4*)(dst + 4)  = *(const float4*)&TRS(rr, cc + 4);
        *(float4*)(dst + 8)  = *(const float4*)&TRS(rr, cc + 8);
        *(float4*)(dst + 12) = *(const float4*)&TRS(rr, cc + 12);
    }
}

#define CAND_CAP 2048
__global__ __launch_bounds__(256, 4) void topk_mask(float* __restrict__ adj) {
    __shared__ float cval[CAND_CAP];
    __shared__ int cidx[CAND_CAP];
    __shared__ int count;
    __shared__ unsigned long long bt[256];
    __shared__ unsigned long long red[4];
    __shared__ unsigned long long bc64;
    int row = blockIdx.x;
    int t = threadIdx.x;
    float* rp = adj + (size_t)row * N_ROWS;
    const float4* rp4 = (const float4*)rp;
    float T = T0;
    int M;
    #pragma unroll 1
    while (true) {
        if (t == 0) count = 0;
        __syncthreads();
        #pragma unroll 1
        for (int c = 0; c < 12; ++c) {
            float4 w = rp4[c * 256 + t];
            int jb = 4 * (c * 256 + t);
            if (w.x > T) { int p = atomicAdd(&count, 1); if (p < CAND_CAP) { cval[p] = w.x; cidx[p] = jb + 0; } }
            if (w.y > T) { int p = atomicAdd(&count, 1); if (p < CAND_CAP) { cval[p] = w.y; cidx[p] = jb + 1; } }
            if (w.z > T) { int p = atomicAdd(&count, 1); if (p < CAND_CAP) { cval[p] = w.z; cidx[p] = jb + 2; } }
            if (w.w > T) { int p = atomicAdd(&count, 1); if (p < CAND_CAP) { cval[p] = w.w; cidx[p] = jb + 3; } }
        }
        __syncthreads();
        M = count < CAND_CAP ? count : CAND_CAP;
        if (M >= K_TOP) break;
        T -= 0.03f;
        __syncthreads();
    }
    unsigned long long cutoff;
    if (M <= 256) {
        unsigned long long v = (t < M) ? composite(cval[t], cidx[t]) : 0ULL;
        #pragma unroll 1
        for (int k = 2; k <= 256; k <<= 1) {
            #pragma unroll 1
            for (int j = k >> 1; j >= 1; j >>= 1) {
                unsigned long long other;
                if (j >= 64) {
                    bt[t] = v;
                    __syncthreads();
                    other = bt[t ^ j];
                    __syncthreads();
                } else {
                    other = shfl_xor_u64(v, j);
                }
                bool down = ((t & k) == 0);
                bool lower = ((t & j) == 0);
                bool take_max = (down == lower);
                bool omax = (other > v);
                v = (take_max == omax) ? other : v;
            }
        }
        if (t == 31) bc64 = v;
        __syncthreads();
        cutoff = bc64;
    } else {
        cutoff = 0;
        #pragma unroll 1
        for (int r2 = 0; r2 < K_TOP; ++r2) {
            unsigned long long best = 0;
            for (int p2 = t; p2 < M; p2 += 256) {
                int id = cidx[p2];
                if (id >= 0) {
                    unsigned long long comp = composite(cval[p2], id);
                    if (comp > best) best = comp;
                }
            }
            #pragma unroll
            for (int off = 32; off > 0; off >>= 1) {
                unsigned long long o = shfl_down_u64(best, off);
                if (o > best) best = o;
            }
            if ((t & 63) == 0) red[t >> 6] = best;
            __syncthreads();
            unsigned long long win = red[0];
            if (red[1] > win) win = red[1];
            if (red[2] > win) win = red[2];
            if (red[3] > win) win = red[3];
            cutoff = win;
            int jwin = N_ROWS - (int)(win & 0xFFFFFFFFu);
            __syncthreads();
            for (int p2 = t; p2 < M; p2 += 256)
                if (cidx[p2] == jwin) cidx[p2] = -1;
            __syncthreads();
        }
    }
    #pragma unroll 1
    for (int c = 0; c < 12; ++c) {
        float4 w = rp4[c * 256 + t];
        int jb = 4 * (c * 256 + t);
        float4 o;
        o.x = (composite(w.x, jb + 0) >= cutoff) ? w.x : 0.0f;
        o.y = (composite(w.y, jb + 1) >= cutoff) ? w.y : 0.0f;
        o.z = (composite(w.z, jb + 2) >= cutoff) ? w.z : 0.0f;
        o.w = (composite(w.w, jb + 3) >= cutoff) ? w.w : 0.0f;
        ((float4*)rp)[c * 256 + t] = o;
    }
}

extern "C" void kernel_launch(void* const* d_in, const int* in_sizes, int n_in,
                              void* d_out, int out_size, void* d_ws, size_t ws_size,
                              hipStream_t stream) {
    const float* x = (const float*)d_in[0];
    float* out = (float*)d_out;

    const size_t xn_b = (size_t)N_ROWS * DIM * 4;
    const size_t cnt_b = (size_t)N_ROWS * 4;
    const size_t need = xn_b + 2 * cnt_b + (size_t)N_ROWS * CAP * 8;

    float* xn = (float*)d_ws;
    normalize_rows<<<N_ROWS, 256, 0, stream>>>(x, xn);

    if (ws_size >= need) {
        int* counts = (int*)((char*)d_ws + xn_b);
        int* flags = (int*)((char*)d_ws + xn_b + cnt_b);
        unsigned long long* cand = (unsigned long long*)((char*)d_ws + xn_b + 2 * cnt_b);
        hipMemsetAsync(counts, 0, 2 * cnt_b, stream);           // counts + flags
        hipMemsetAsync(out, 0, (size_t)out_size * 4, stream);   // dense zero output
        gemm_push<<<NT * (NT + 1) / 2, 256, 0, stream>>>(xn, cand, counts);
        select_scatter<<<N_ROWS, 256, 0, stream>>>(cand, counts, flags, out);
        rescue_rows<<<N_ROWS, 256, 0, stream>>>(xn, flags, out);
    } else {
        gemm_sym_dense<<<NT * (NT + 1) / 2, 256, 0, stream>>>(xn, out);
        topk_mask<<<N_ROWS, 256, 0, stream>>>(out);
    }
}

// Round 9
// 920.686 us; speedup vs baseline: 1.9803x; 1.7005x over previous
//
#include <hip/hip_runtime.h>
#include <math.h>

#define N_ROWS 12288
#define DIM 256
#define K_TOP 32
#define CAP 240          // candidate slots per row (mean ~125, P(>240) ~ 0)
#define T0 0.145f        // push threshold; rank-32 boundary ~0.175 (z=2.79)
#define ECAP 2048        // block-local LDS entry cap (expected ~330/block)
#define GAP_MARGIN 1.0e-4f  // rank32-rank33 gap below which row is re-done

typedef unsigned short u16;
typedef unsigned int u32;
typedef unsigned long long u64;
typedef __attribute__((ext_vector_type(8))) short bf16x8;   // 8 bf16 = 4 VGPRs
typedef __attribute__((ext_vector_type(16))) float f32x16;  // MFMA 32x32 acc

// ---------------- key helpers ----------------
__device__ __forceinline__ u32 f2key(float f) {
    u32 u = __float_as_uint(f);
    return (u & 0x80000000u) ? ~u : (u | 0x80000000u);
}
__device__ __forceinline__ float key2f(u32 k) {
    u32 u = (k & 0x80000000u) ? (k ^ 0x80000000u) : ~k;
    return __uint_as_float(u);
}
__device__ __forceinline__ u64 composite(float v, int j) {
    return ((u64)f2key(v) << 32) | (u32)(N_ROWS - j);
}
__device__ __forceinline__ u64 shfl_xor_u64(u64 x, int m) {
    u32 lo = (u32)x, hi = (u32)(x >> 32);
    lo = __shfl_xor(lo, m, 64);
    hi = __shfl_xor(hi, m, 64);
    return ((u64)hi << 32) | lo;
}
__device__ __forceinline__ u64 shfl_down_u64(u64 x, int off) {
    u32 lo = (u32)x, hi = (u32)(x >> 32);
    lo = __shfl_down(lo, off, 64);
    hi = __shfl_down(hi, off, 64);
    return ((u64)hi << 32) | lo;
}
__device__ __forceinline__ u16 f32_to_bf16(float f) {
    u32 u = __float_as_uint(f);
    return (u16)((u + 0x7FFFu + ((u >> 16) & 1u)) >> 16);   // RNE
}

// bitonic-256 descending sort across the block; returns element at position t.
__device__ u64 bitonic256_desc(u64 v, int t, u64* bt) {
    #pragma unroll 1
    for (int k = 2; k <= 256; k <<= 1) {
        #pragma unroll 1
        for (int j = k >> 1; j >= 1; j >>= 1) {
            u64 other;
            if (j >= 64) {
                bt[t] = v;
                __syncthreads();
                other = bt[t ^ j];
                __syncthreads();
            } else {
                other = shfl_xor_u64(v, j);
            }
            bool down = ((t & k) == 0);
            bool lower = ((t & j) == 0);
            bool take_max = (down == lower);
            bool omax = (other > v);
            v = (take_max == omax) ? other : v;
        }
    }
    return v;
}

// ---------------- Kernel 1 (main): normalize (division) + bf16 hi/lo split ----------------
__global__ __launch_bounds__(256) void normalize_split(const float* __restrict__ x,
                                                       u16* __restrict__ hi,
                                                       u16* __restrict__ lo,
                                                       float* __restrict__ nrm) {
    int row = blockIdx.x;
    int t = threadIdx.x;
    float v = x[(size_t)row * DIM + t];
    float sq = v * v;
    #pragma unroll
    for (int off = 32; off > 0; off >>= 1)
        sq += __shfl_down(sq, off, 64);
    __shared__ float ws[4];
    if ((t & 63) == 0) ws[t >> 6] = sq;
    __syncthreads();
    float total = ws[0] + ws[1] + ws[2] + ws[3];
    float nr = fmaxf(sqrtf(total), 1e-12f);
    if (t == 0) nrm[row] = nr;
    float xnv = v / nr;                 // division — matches R1-R6 xn numerics
    u16 h = f32_to_bf16(xnv);
    float hf = __uint_as_float(((u32)h) << 16);
    u16 l = f32_to_bf16(xnv - hf);
    hi[(size_t)row * DIM + t] = h;
    lo[(size_t)row * DIM + t] = l;
}

// ---------------- Kernel 2 (main): split-bf16 MFMA GEMM + candidate push ----------------
// C/D layout (m74/m101): col=lane&31, row=(reg&3)+8*(reg>>2)+4*(lane>>5).
// NOTE: acc indices must be compile-time (R3 lesson: scratch demotion).
#define NTB (N_ROWS / 128)   // 96

__global__ __launch_bounds__(256) void gemm_mfma_push(const u16* __restrict__ Ahi,
                                                      const u16* __restrict__ Alo,
                                                      u64* __restrict__ cand,
                                                      int* __restrict__ counts) {
    __shared__ u16 smem_u[2 * 4 * 2048];   // 32 KB

    int L = blockIdx.x;
    int bi = (int)((sqrtf(8.0f * (float)L + 1.0f) - 1.0f) * 0.5f);
    while ((bi + 1) * (bi + 2) / 2 <= L) ++bi;
    while (bi * (bi + 1) / 2 > L) --bi;
    int bj = L - bi * (bi + 1) / 2;

    int tid = threadIdx.x;
    int lane = tid & 63;
    int w = tid >> 6;
    int wrow = w >> 1, wcol = w & 1;

    int srow = tid >> 1, shalf = tid & 1;
    size_t ofsA = (size_t)(bi * 128 + srow) * DIM + shalf * 8;
    size_t ofsB = (size_t)(bj * 128 + srow) * DIM + shalf * 8;
    const u16* pAhi = Ahi + ofsA;
    const u16* pAlo = Alo + ofsA;
    const u16* pBhi = Ahi + ofsB;
    const u16* pBlo = Alo + ofsB;
    int sdst = srow * 16 + shalf * 8;

    int arow0 = (wrow * 64 + (lane & 31)) * 16 + (lane >> 5) * 8;
    int arow1 = arow0 + 32 * 16;
    int brow0 = (wcol * 64 + (lane & 31)) * 16 + (lane >> 5) * 8;
    int brow1 = brow0 + 32 * 16;

    f32x16 acc0 = {}, acc1 = {}, acc2 = {}, acc3 = {};

    uint4 rAh = *(const uint4*)(pAhi);
    uint4 rAl = *(const uint4*)(pAlo);
    uint4 rBh = *(const uint4*)(pBhi);
    uint4 rBl = *(const uint4*)(pBlo);
    *(uint4*)&smem_u[0 * 2048 + sdst] = rAh;
    *(uint4*)&smem_u[1 * 2048 + sdst] = rAl;
    *(uint4*)&smem_u[2 * 2048 + sdst] = rBh;
    *(uint4*)&smem_u[3 * 2048 + sdst] = rBl;
    __syncthreads();

    int p = 0;
    #pragma unroll 1
    for (int it = 0; it < DIM / 16; ++it) {
        bool has_next = (it + 1) < (DIM / 16);
        if (has_next) {
            int k0 = (it + 1) * 16;
            rAh = *(const uint4*)(pAhi + k0);
            rAl = *(const uint4*)(pAlo + k0);
            rBh = *(const uint4*)(pBhi + k0);
            rBl = *(const uint4*)(pBlo + k0);
        }
        const u16* base = &smem_u[p * 8192];
        bf16x8 ah0 = *(const bf16x8*)&base[0 * 2048 + arow0];
        bf16x8 ah1 = *(const bf16x8*)&base[0 * 2048 + arow1];
        bf16x8 al0 = *(const bf16x8*)&base[1 * 2048 + arow0];
        bf16x8 al1 = *(const bf16x8*)&base[1 * 2048 + arow1];
        bf16x8 bh0 = *(const bf16x8*)&base[2 * 2048 + brow0];
        bf16x8 bh1 = *(const bf16x8*)&base[2 * 2048 + brow1];
        bf16x8 bl0 = *(const bf16x8*)&base[3 * 2048 + brow0];
        bf16x8 bl1 = *(const bf16x8*)&base[3 * 2048 + brow1];

        acc0 = __builtin_amdgcn_mfma_f32_32x32x16_bf16(ah0, bh0, acc0, 0, 0, 0);
        acc0 = __builtin_amdgcn_mfma_f32_32x32x16_bf16(ah0, bl0, acc0, 0, 0, 0);
        acc0 = __builtin_amdgcn_mfma_f32_32x32x16_bf16(al0, bh0, acc0, 0, 0, 0);
        acc1 = __builtin_amdgcn_mfma_f32_32x32x16_bf16(ah0, bh1, acc1, 0, 0, 0);
        acc1 = __builtin_amdgcn_mfma_f32_32x32x16_bf16(ah0, bl1, acc1, 0, 0, 0);
        acc1 = __builtin_amdgcn_mfma_f32_32x32x16_bf16(al0, bh1, acc1, 0, 0, 0);
        acc2 = __builtin_amdgcn_mfma_f32_32x32x16_bf16(ah1, bh0, acc2, 0, 0, 0);
        acc2 = __builtin_amdgcn_mfma_f32_32x32x16_bf16(ah1, bl0, acc2, 0, 0, 0);
        acc2 = __builtin_amdgcn_mfma_f32_32x32x16_bf16(al1, bh0, acc2, 0, 0, 0);
        acc3 = __builtin_amdgcn_mfma_f32_32x32x16_bf16(ah1, bh1, acc3, 0, 0, 0);
        acc3 = __builtin_amdgcn_mfma_f32_32x32x16_bf16(ah1, bl1, acc3, 0, 0, 0);
        acc3 = __builtin_amdgcn_mfma_f32_32x32x16_bf16(al1, bh1, acc3, 0, 0, 0);

        if (has_next) {
            int np = p ^ 1;
            u16* nb = &smem_u[np * 8192];
            *(uint4*)&nb[0 * 2048 + sdst] = rAh;
            *(uint4*)&nb[1 * 2048 + sdst] = rAl;
            *(uint4*)&nb[2 * 2048 + sdst] = rBh;
            *(uint4*)&nb[3 * 2048 + sdst] = rBl;
        }
        __syncthreads();
        p ^= 1;
    }

    // ---- epilogue: LDS-aggregated candidate push ----
    u32* su = (u32*)smem_u;
    u32* lcount = su;
    u32* cnt2 = su + 8;
    u32* cnt3 = su + 264;
    u32* basep = su + 520;
    u64* ent = (u64*)(su + 776);

    if (tid == 0) *lcount = 0;
    cnt2[tid] = 0;
    cnt3[tid] = 0;
    __syncthreads();

    bool diag = (bi == bj);
    int rbaseA = wrow * 64 + 4 * (lane >> 5);
    int cbase = wcol * 64 + (lane & 31);

#define PUSH_TILE(ACC, RT, CT)                                                 \
    _Pragma("unroll")                                                          \
    for (int q = 0; q < 16; ++q) {                                             \
        float v = ACC[q];                                                      \
        if (v > T0) {                                                          \
            int rlA = rbaseA + (RT) * 32 + (q & 3) + 8 * (q >> 2);             \
            int clB = cbase + (CT) * 32;                                       \
            int gr = bi * 128 + rlA;                                           \
            int gc = bj * 128 + clB;                                           \
            u32 key = f2key(v);                                                \
            u32 s = atomicAdd(lcount, 1u);                                     \
            if (s < ECAP) {                                                    \
                ent[s] = ((u64)key << 32) | ((u32)rlA << 14) | (u32)gc;        \
                atomicAdd(&cnt2[rlA], 1u);                                     \
            } else {                                                           \
                int gs = atomicAdd(&counts[gr], 1);                            \
                if (gs < CAP) cand[(size_t)gr * CAP + gs] =                    \
                    ((u64)key << 32) | (u32)(N_ROWS - gc);                     \
            }                                                                  \
            if (!diag) {                                                       \
                u32 s2 = atomicAdd(lcount, 1u);                                \
                if (s2 < ECAP) {                                               \
                    ent[s2] = ((u64)key << 32) | ((u32)(128 + clB) << 14) | (u32)gr; \
                    atomicAdd(&cnt2[128 + clB], 1u);                           \
                } else {                                                       \
                    int gs2 = atomicAdd(&counts[gc], 1);                       \
                    if (gs2 < CAP) cand[(size_t)gc * CAP + gs2] =              \
                        ((u64)key << 32) | (u32)(N_ROWS - gr);                 \
                }                                                              \
            }                                                                  \
        }                                                                      \
    }

    PUSH_TILE(acc0, 0, 0)
    PUSH_TILE(acc1, 0, 1)
    PUSH_TILE(acc2, 1, 0)
    PUSH_TILE(acc3, 1, 1)
#undef PUSH_TILE
    __syncthreads();

    {
        u32 c = cnt2[tid];
        if (c > 0) {
            int grow = (tid < 128) ? (bi * 128 + tid) : (bj * 128 + (tid - 128));
            basep[tid] = (u32)atomicAdd(&counts[grow], (int)c);
        }
    }
    __syncthreads();

    u32 nloc = *lcount;
    if (nloc > ECAP) nloc = ECAP;
    for (u32 e = tid; e < nloc; e += 256) {
        u64 en = ent[e];
        u32 elo = (u32)en;
        int rl = (int)((elo >> 14) & 0xFFu);
        int col = (int)(elo & 0x3FFFu);
        u32 key = (u32)(en >> 32);
        u32 off = atomicAdd(&cnt3[rl], 1u);
        u32 slot = basep[rl] + off;
        if (slot < CAP) {
            int grow = (rl < 128) ? (bi * 128 + rl) : (bj * 128 + (rl - 128));
            cand[(size_t)grow * CAP + slot] = ((u64)key << 32) | (u32)(N_ROWS - col);
        }
    }
}

// ---------------- Kernel 3 (main): zero row + select top-32 + scatter ----------------
__global__ __launch_bounds__(256) void select_scatter_zero(const u64* __restrict__ cand,
                                                           const int* __restrict__ counts,
                                                           int* __restrict__ flags,
                                                           float* __restrict__ out) {
    __shared__ u64 bt[256];
    __shared__ u64 bc64;
    __shared__ float g2[2];
    int row = blockIdx.x;
    int t = threadIdx.x;
    float4* rp4 = (float4*)(out + (size_t)row * N_ROWS);
    float4 z = make_float4(0.0f, 0.0f, 0.0f, 0.0f);
    #pragma unroll
    for (int c = 0; c < 12; ++c) rp4[c * 256 + t] = z;

    int cnt = counts[row];
    if (cnt < K_TOP || cnt > CAP) {
        if (t == 0) flags[row] = 2;     // full rescue
        return;
    }
    int M = cnt;
    u64 v = (t < M) ? cand[(size_t)row * CAP + t] : 0ULL;
    v = bitonic256_desc(v, t, bt);
    if (t == 31) { bc64 = v; g2[0] = key2f((u32)(v >> 32)); }
    if (t == 32) g2[1] = (M > 32) ? key2f((u32)(v >> 32)) : T0;
    __syncthreads();
    if (g2[0] - g2[1] < GAP_MARGIN) {
        if (t == 0) flags[row] = 1;     // candidate rescue (R1-R6 numerics)
        return;
    }
    u64 cutoff = bc64;
    if (t < M) {
        u64 comp = cand[(size_t)row * CAP + t];
        if (comp >= cutoff) {
            int col = N_ROWS - (int)(comp & 0xFFFFFFFFu);
            out[(size_t)row * N_ROWS + col] = key2f((u32)(comp >> 32));
        }
    }
}

// ---------------- Kernel 4 (main): rescue over candidates, R1-R6 numerics ----------------
// CRITICAL: reproduces the empirically-reference-matching arithmetic from
// rounds 1-6 BIT-FOR-BIT: xn by division, fp32 fmaf accumulation in strictly
// sequential k order (0..255). Do NOT "improve" to fp64 — the reference's own
// fp32 noise decides ties; exact math provably mismatches (R7/R8 failures).
__global__ __launch_bounds__(256) void rescue_cand(const float* __restrict__ x,
                                                   const float* __restrict__ nrm,
                                                   const u64* __restrict__ cand,
                                                   const int* __restrict__ counts,
                                                   const int* __restrict__ flags,
                                                   float* __restrict__ out) {
    int row = blockIdx.x;
    if (flags[row] != 1) return;
    __shared__ float xrow_n[DIM];
    __shared__ u64 cmp[256];
    __shared__ u64 bt[256];
    __shared__ u64 bc64;
    int t = threadIdx.x;
    float nr = nrm[row];
    xrow_n[t] = x[(size_t)row * DIM + t] / nr;
    __syncthreads();
    int cnt = counts[row];              // K_TOP <= cnt <= CAP
    u64 v = 0;
    if (t < cnt) {
        u64 oldc = cand[(size_t)row * CAP + t];
        int col = N_ROWS - (int)(oldc & 0xFFFFFFFFu);
        float rcn = nrm[col];
        const float4* xc = (const float4*)(x + (size_t)col * DIM);
        float s = 0.0f;
        #pragma unroll 4
        for (int d = 0; d < DIM / 4; ++d) {
            float4 wv = xc[d];
            s = fmaf(xrow_n[4 * d + 0], wv.x / rcn, s);
            s = fmaf(xrow_n[4 * d + 1], wv.y / rcn, s);
            s = fmaf(xrow_n[4 * d + 2], wv.z / rcn, s);
            s = fmaf(xrow_n[4 * d + 3], wv.w / rcn, s);
        }
        v = composite(s, col);
    }
    cmp[t] = v;
    __syncthreads();
    u64 sv = bitonic256_desc(v, t, bt);
    if (t == 31) bc64 = sv;
    __syncthreads();
    u64 cutoff = bc64;
    if (t < cnt && cmp[t] >= cutoff) {
        int col = N_ROWS - (int)(cmp[t] & 0xFFFFFFFFu);
        out[(size_t)row * N_ROWS + col] = key2f((u32)(cmp[t] >> 32));
    }
}

// ---------------- Kernel 5 (main): full rescue (~never), same R1-R6 numerics ----------------
__global__ __launch_bounds__(256) void rescue_full(const float* __restrict__ x,
                                                   const float* __restrict__ nrm,
                                                   const int* __restrict__ flags,
                                                   float* __restrict__ out) {
    int row = blockIdx.x;
    if (flags[row] != 2) return;
    __shared__ float xrow_n[DIM];
    __shared__ float sims[N_ROWS];      // 48 KB
    __shared__ u64 red[4];
    int t = threadIdx.x;
    xrow_n[t] = x[(size_t)row * DIM + t] / nrm[row];
    __syncthreads();
    for (int j = t; j < N_ROWS; j += 256) {
        float rcn = nrm[j];
        const float4* xc = (const float4*)(x + (size_t)j * DIM);
        float s = 0.0f;
        for (int d = 0; d < DIM / 4; ++d) {
            float4 wv = xc[d];
            s = fmaf(xrow_n[4 * d + 0], wv.x / rcn, s);
            s = fmaf(xrow_n[4 * d + 1], wv.y / rcn, s);
            s = fmaf(xrow_n[4 * d + 2], wv.z / rcn, s);
            s = fmaf(xrow_n[4 * d + 3], wv.w / rcn, s);
        }
        sims[j] = s;
    }
    __syncthreads();
    #pragma unroll 1
    for (int r2 = 0; r2 < K_TOP; ++r2) {
        u64 best = 0;
        for (int k = 0; k < N_ROWS / 256; ++k) {
            int j = t + 256 * k;
            u64 c = composite(sims[j], j);
            if (c > best) best = c;
        }
        #pragma unroll
        for (int off = 32; off > 0; off >>= 1) {
            u64 o = shfl_down_u64(best, off);
            if (o > best) best = o;
        }
        if ((t & 63) == 0) red[t >> 6] = best;
        __syncthreads();
        if (t == 0) {
            u64 win = red[0];
            if (red[1] > win) win = red[1];
            if (red[2] > win) win = red[2];
            if (red[3] > win) win = red[3];
            int jwin = N_ROWS - (int)(win & 0xFFFFFFFFu);
            out[(size_t)row * N_ROWS + jwin] = key2f((u32)(win >> 32));
            sims[jwin] = -1e30f;
        }
        __syncthreads();
    }
}

// ======================= Fallback path (small ws): dense fp32 =======================
__global__ __launch_bounds__(256) void normalize_rows(const float* __restrict__ x,
                                                      float* __restrict__ xn) {
    int row = blockIdx.x;
    int t = threadIdx.x;
    float v = x[(size_t)row * DIM + t];
    float sq = v * v;
    #pragma unroll
    for (int off = 32; off > 0; off >>= 1)
        sq += __shfl_down(sq, off, 64);
    __shared__ float ws[4];
    if ((t & 63) == 0) ws[t >> 6] = sq;
    __syncthreads();
    float total = ws[0] + ws[1] + ws[2] + ws[3];
    float norm = fmaxf(sqrtf(total), 1e-12f);
    xn[(size_t)row * DIM + t] = v / norm;
}

#define BM 128
#define BN 128
#define BK 16
#define BMP 132
#define TRP 140

#define AS(buf, k, r) smem[(buf)*(2*BK*BMP) + (k)*BMP + (r)]
#define BS(buf, k, r) smem[(buf)*(2*BK*BMP) + (BK*BMP) + (k)*BMP + (r)]
#define TRS(r, c)     smem[(r)*TRP + (c)]

__global__ __launch_bounds__(256) void gemm_sym_dense(const float* __restrict__ A,
                                                      float* __restrict__ C) {
    __shared__ float smem[2 * 2 * BK * BMP];
    int L = blockIdx.x;
    int bi = (int)((sqrtf(8.0f * (float)L + 1.0f) - 1.0f) * 0.5f);
    while ((bi + 1) * (bi + 2) / 2 <= L) ++bi;
    while (bi * (bi + 1) / 2 > L) --bi;
    int bj = L - bi * (bi + 1) / 2;
    int tid = threadIdx.x;
    int tx = tid & 15, ty = tid >> 4;
    int tx4 = tx * 4, ty4 = ty * 4;
    int r0 = tid >> 2, q0 = tid & 3;
    const float* Abase = A + (size_t)(bi * BM) * DIM;
    const float* Bbase = A + (size_t)(bj * BN) * DIM;
    float acc[8][8] = {};
    float4 pa0, pa1, pb0, pb1;
    pa0 = *(const float4*)(Abase + (size_t)r0 * DIM + q0 * 4);
    pa1 = *(const float4*)(Abase + (size_t)(r0 + 64) * DIM + q0 * 4);
    pb0 = *(const float4*)(Bbase + (size_t)r0 * DIM + q0 * 4);
    pb1 = *(const float4*)(Bbase + (size_t)(r0 + 64) * DIM + q0 * 4);
    {
        const float* a0 = (const float*)&pa0; const float* a1 = (const float*)&pa1;
        const float* b0 = (const float*)&pb0; const float* b1 = (const float*)&pb1;
        #pragma unroll
        for (int c = 0; c < 4; ++c) {
            AS(0, q0 * 4 + c, r0) = a0[c];  AS(0, q0 * 4 + c, r0 + 64) = a1[c];
            BS(0, q0 * 4 + c, r0) = b0[c];  BS(0, q0 * 4 + c, r0 + 64) = b1[c];
        }
    }
    __syncthreads();
    int p = 0;
    #pragma unroll 1
    for (int it = 0; it < DIM / BK; ++it) {
        bool has_next = (it + 1) < (DIM / BK);
        if (has_next) {
            int k0 = (it + 1) * BK;
            pa0 = *(const float4*)(Abase + (size_t)r0 * DIM + k0 + q0 * 4);
            pa1 = *(const float4*)(Abase + (size_t)(r0 + 64) * DIM + k0 + q0 * 4);
            pb0 = *(const float4*)(Bbase + (size_t)r0 * DIM + k0 + q0 * 4);
            pb1 = *(const float4*)(Bbase + (size_t)(r0 + 64) * DIM + k0 + q0 * 4);
        }
        #pragma unroll
        for (int kk = 0; kk < BK; ++kk) {
            float a[8], b[8];
            *(float4*)&a[0] = *(const float4*)&AS(p, kk, ty4);
            *(float4*)&a[4] = *(const float4*)&AS(p, kk, ty4 + 64);
            *(float4*)&b[0] = *(const float4*)&BS(p, kk, tx4);
            *(float4*)&b[4] = *(const float4*)&BS(p, kk, tx4 + 64);
            #pragma unroll
            for (int i = 0; i < 8; ++i)
                #pragma unroll
                for (int j = 0; j < 8; ++j)
                    acc[i][j] = fmaf(a[i], b[j], acc[i][j]);
        }
        if (has_next) {
            int np = p ^ 1;
            const float* a0 = (const float*)&pa0; const float* a1 = (const float*)&pa1;
            const float* b0 = (const float*)&pb0; const float* b1 = (const float*)&pb1;
            #pragma unroll
            for (int c = 0; c < 4; ++c) {
                AS(np, q0 * 4 + c, r0) = a0[c];  AS(np, q0 * 4 + c, r0 + 64) = a1[c];
                BS(np, q0 * 4 + c, r0) = b0[c];  BS(np, q0 * 4 + c, r0 + 64) = b1[c];
            }
        }
        __syncthreads();
        p ^= 1;
    }
    #pragma unroll
    for (int i = 0; i < 8; ++i) {
        int rl = ty4 + (i & 3) + (i >> 2) * 64;
        float* outp = C + (size_t)(bi * BM + rl) * N_ROWS + bj * BN;
        *(float4*)(outp + tx4)      = *(float4*)&acc[i][0];
        *(float4*)(outp + 64 + tx4) = *(float4*)&acc[i][4];
    }
    if (bi == bj) return;
    #pragma unroll
    for (int c4 = 0; c4 < 4; ++c4) {
        __syncthreads();
        if ((tx >> 3) == (c4 & 1)) {
            #pragma unroll
            for (int j03 = 0; j03 < 4; ++j03)
                #pragma unroll
                for (int i = 0; i < 8; ++i) {
                    int rl = ty4 + (i & 3) + (i >> 2) * 64;
                    TRS((tx & 7) * 4 + j03, rl) = acc[i][(c4 >> 1) * 4 + j03];
                }
        }
        __syncthreads();
        int rr = tid >> 3;
        int cc = (tid & 7) * 16;
        float* dst = C + (size_t)(bj * BN + c4 * 32 + rr) * N_ROWS + bi * BM + cc;
        *(float4*)(dst + 0)  = *(const float4*)&TRS(rr, cc + 0);
        *(float4*)(dst + 4)  = *(const float4*)&TRS(rr, cc + 4);
        *(float4*)(dst + 8)  = *(const float4*)&TRS(rr, cc + 8);
        *(float4*)(dst + 12) = *(const float4*)&TRS(rr, cc + 12);
    }
}

#define CAND_CAP 2048
__global__ __launch_bounds__(256, 4) void topk_mask(float* __restrict__ adj) {
    __shared__ float cval[CAND_CAP];
    __shared__ int cidx[CAND_CAP];
    __shared__ int count;
    __shared__ u64 bt[256];
    __shared__ u64 red[4];
    __shared__ u64 bc64;
    int row = blockIdx.x;
    int t = threadIdx.x;
    float* rp = adj + (size_t)row * N_ROWS;
    const float4* rp4 = (const float4*)rp;
    float T = T0;
    int M;
    #pragma unroll 1
    while (true) {
        if (t == 0) count = 0;
        __syncthreads();
        #pragma unroll 1
        for (int c = 0; c < 12; ++c) {
            float4 w = rp4[c * 256 + t];
            int jb = 4 * (c * 256 + t);
            if (w.x > T) { int p = atomicAdd(&count, 1); if (p < CAND_CAP) { cval[p] = w.x; cidx[p] = jb + 0; } }
            if (w.y > T) { int p = atomicAdd(&count, 1); if (p < CAND_CAP) { cval[p] = w.y; cidx[p] = jb + 1; } }
            if (w.z > T) { int p = atomicAdd(&count, 1); if (p < CAND_CAP) { cval[p] = w.z; cidx[p] = jb + 2; } }
            if (w.w > T) { int p = atomicAdd(&count, 1); if (p < CAND_CAP) { cval[p] = w.w; cidx[p] = jb + 3; } }
        }
        __syncthreads();
        M = count < CAND_CAP ? count : CAND_CAP;
        if (M >= K_TOP) break;
        T -= 0.03f;
        __syncthreads();
    }
    u64 cutoff;
    if (M <= 256) {
        u64 v = (t < M) ? composite(cval[t], cidx[t]) : 0ULL;
        v = bitonic256_desc(v, t, bt);
        if (t == 31) bc64 = v;
        __syncthreads();
        cutoff = bc64;
    } else {
        cutoff = 0;
        #pragma unroll 1
        for (int r2 = 0; r2 < K_TOP; ++r2) {
            u64 best = 0;
            for (int p2 = t; p2 < M; p2 += 256) {
                int id = cidx[p2];
                if (id >= 0) {
                    u64 comp = composite(cval[p2], id);
                    if (comp > best) best = comp;
                }
            }
            #pragma unroll
            for (int off = 32; off > 0; off >>= 1) {
                u64 o = shfl_down_u64(best, off);
                if (o > best) best = o;
            }
            if ((t & 63) == 0) red[t >> 6] = best;
            __syncthreads();
            u64 win = red[0];
            if (red[1] > win) win = red[1];
            if (red[2] > win) win = red[2];
            if (red[3] > win) win = red[3];
            cutoff = win;
            int jwin = N_ROWS - (int)(win & 0xFFFFFFFFu);
            __syncthreads();
            for (int p2 = t; p2 < M; p2 += 256)
                if (cidx[p2] == jwin) cidx[p2] = -1;
            __syncthreads();
        }
    }
    #pragma unroll 1
    for (int c = 0; c < 12; ++c) {
        float4 w = rp4[c * 256 + t];
        int jb = 4 * (c * 256 + t);
        float4 o;
        o.x = (composite(w.x, jb + 0) >= cutoff) ? w.x : 0.0f;
        o.y = (composite(w.y, jb + 1) >= cutoff) ? w.y : 0.0f;
        o.z = (composite(w.z, jb + 2) >= cutoff) ? w.z : 0.0f;
        o.w = (composite(w.w, jb + 3) >= cutoff) ? w.w : 0.0f;
        ((float4*)rp)[c * 256 + t] = o;
    }
}

extern "C" void kernel_launch(void* const* d_in, const int* in_sizes, int n_in,
                              void* d_out, int out_size, void* d_ws, size_t ws_size,
                              hipStream_t stream) {
    const float* x = (const float*)d_in[0];
    float* out = (float*)d_out;

    const size_t hi_b  = (size_t)N_ROWS * DIM * 2;            // 6,291,456
    const size_t nr_b  = (size_t)N_ROWS * 4;                  //    49,152
    const size_t off_lo    = hi_b;
    const size_t off_nrm   = 2 * hi_b;
    const size_t off_cnt   = off_nrm + nr_b;
    const size_t off_flags = off_cnt + nr_b;
    const size_t off_cand  = off_flags + nr_b;
    const size_t need_main = off_cand + (size_t)N_ROWS * CAP * 8;  // 36,323,328

    if (ws_size >= need_main) {
        u16* hi = (u16*)d_ws;
        u16* lo = (u16*)((char*)d_ws + off_lo);
        float* nrm = (float*)((char*)d_ws + off_nrm);
        int* counts = (int*)((char*)d_ws + off_cnt);
        int* flags = (int*)((char*)d_ws + off_flags);
        u64* cand = (u64*)((char*)d_ws + off_cand);

        normalize_split<<<N_ROWS, 256, 0, stream>>>(x, hi, lo, nrm);
        hipMemsetAsync(counts, 0, 2 * nr_b, stream);   // counts + flags
        gemm_mfma_push<<<NTB * (NTB + 1) / 2, 256, 0, stream>>>(hi, lo, cand, counts);
        select_scatter_zero<<<N_ROWS, 256, 0, stream>>>(cand, counts, flags, out);
        rescue_cand<<<N_ROWS, 256, 0, stream>>>(x, nrm, cand, counts, flags, out);
        rescue_full<<<N_ROWS, 256, 0, stream>>>(x, nrm, flags, out);
    } else {
        float* xn = (float*)d_ws;   // 12.6 MB
        normalize_rows<<<N_ROWS, 256, 0, stream>>>(x, xn);
        gemm_sym_dense<<<NTB * (NTB + 1) / 2, 256, 0, stream>>>(xn, out);
        topk_mask<<<N_ROWS, 256, 0, stream>>>(out);
    }
}